// Round 4
// baseline (228.479 us; speedup 1.0000x reference)
//
#include <hip/hip_runtime.h>
#include <stdint.h>

#define MM 16384
#define KK 2048
#define NN 2048
#define GG 64
#define EPSV 1e-5f
#define NTK 64          // K tiles of 32

typedef short short8 __attribute__((ext_vector_type(8)));
typedef float floatx4 __attribute__((ext_vector_type(4)));

__device__ __forceinline__ uint16_t f2bf(float f) {
  uint32_t u = __float_as_uint(f);
  u = (u + 0x7fffu + ((u >> 16) & 1u)) >> 16;
  return (uint16_t)u;
}

__global__ void cvt_f32_to_bf16(const float* __restrict__ src,
                                uint16_t* __restrict__ dst, int n4) {
  int stride = gridDim.x * blockDim.x;
  for (int i = blockIdx.x * blockDim.x + threadIdx.x; i < n4; i += stride) {
    float4 v = reinterpret_cast<const float4*>(src)[i];
    ushort4 o;
    o.x = f2bf(v.x); o.y = f2bf(v.y); o.z = f2bf(v.z); o.w = f2bf(v.w);
    reinterpret_cast<ushort4*>(dst)[i] = o;
  }
}

__device__ __forceinline__ void gload_lds16(const void* g, void* l) {
  __builtin_amdgcn_global_load_lds(
      (const __attribute__((address_space(1))) void*)g,
      (__attribute__((address_space(3))) void*)l, 16, 0, 0);
}

#define BAR() __asm__ volatile("s_barrier" ::: "memory")
#define VMC6() __asm__ volatile("s_waitcnt vmcnt(6)" ::: "memory")
#define VMC0() __asm__ volatile("s_waitcnt vmcnt(0)" ::: "memory")

// r4: tile 128x256 (MxN), 4 waves (1M x 4N), per-wave 128x64, BK=32.
// LDS per block: 2 bufs x (A[128][32] 8KB + B[256][32] 16KB) = 48KB
// -> 2 blocks/CU; cross-block overlap fills barrier/LDS-drain stalls.
// 64B-row swizzle: slot ^= (row ^ (row>>2)) & 3 (fragment-invariant,
// worst 2-way bank aliasing = free). Source pre-swizzled, LDS dest linear.
// Counted vmcnt(6) per tile (6 stage loads/tile), vmcnt(0) only at last.
__global__ __launch_bounds__(256, 2)
void gemm_gn_silu_2b(const uint16_t* __restrict__ xb,  // M x K bf16
                     const uint16_t* __restrict__ wb,  // N x K bf16
                     const float* __restrict__ bias,   // N
                     const float* __restrict__ gnw,    // G
                     const float* __restrict__ gnb,    // G
                     const float* __restrict__ mw,     // N
                     float* __restrict__ out) {        // M x N f32
  extern __shared__ char lds[];   // 49152 bytes

  int bid = blockIdx.x;
  // XCD chunk swizzle: 1024 blocks, 8 XCDs, 128 consecutive per XCD.
  int wgs = ((bid & 7) << 7) | (bid >> 3);
  int tm = wgs >> 3;          // 0..127 (M tiles of 128)
  int tn = wgs & 7;           // 0..7   (N tiles of 256)
  int row0 = tm * 128;
  int col0 = tn * 256;

  int t = threadIdx.x;
  int lane = t & 63;
  int wn = t >> 6;                    // wave id = N position (0..3)
  int llo = lane & 15, lhi = lane >> 4;

  const char* xgb = (const char*)xb + (size_t)row0 * (KK * 2);
  const char* wgb = (const char*)wb + (size_t)col0 * (KK * 2);

  // ---- staging maps (dest linear, source slot pre-swizzled) ----
  // LDS row = 64 bytes (32 k * 2B). dest offset o: row=o>>6, slot=(o>>4)&3.
  // physical slot p holds logical slot p ^ s(row), s(row)=(row^(row>>2))&3.
  int ldsOffA[2], gOffA[2];
  #pragma unroll
  for (int c = 0; c < 2; ++c) {
    int o = c * 4096 + t * 16;
    int row = o >> 6;
    int slot = (o >> 4) & 3;
    int sl = slot ^ ((row ^ (row >> 2)) & 3);
    ldsOffA[c] = o;
    gOffA[c] = row * (KK * 2) + sl * 16;
  }
  int ldsOffB[4], gOffB[4];
  #pragma unroll
  for (int c = 0; c < 4; ++c) {
    int o = c * 4096 + t * 16;
    int row = o >> 6;
    int slot = (o >> 4) & 3;
    int sl = slot ^ ((row ^ (row >> 2)) & 3);
    ldsOffB[c] = 8192 + o;
    gOffB[c] = row * (KK * 2) + sl * 16;
  }

  auto stage = [&](int buf, int kt) {
    if (kt < NTK) {
      const char* sa = xgb + (size_t)kt * 64;
      const char* sb = wgb + (size_t)kt * 64;
      char* d = lds + buf * 24576;
      #pragma unroll
      for (int c = 0; c < 2; ++c) gload_lds16(sa + gOffA[c], d + ldsOffA[c]);
      #pragma unroll
      for (int c = 0; c < 4; ++c) gload_lds16(sb + gOffB[c], d + ldsOffB[c]);
    }
  };

  // ---- fragment read offsets (fragment-invariant swizzle) ----
  // A row r = mi*16+llo, B row c = wn*64+ni*16+llo; s(r) = (llo^(llo>>2))&3.
  uint32_t ko = (uint32_t)((lhi ^ ((llo ^ (llo >> 2)) & 3)) << 4);
  uint32_t aBase = (uint32_t)llo * 64 + ko;
  uint32_t bBase = 8192u + (uint32_t)(wn * 64 + llo) * 64 + ko;

  short8 a[8], b[4];
  floatx4 acc[8][4] = {};

  // Prologue: stage tile 0 into buf 0.
  stage(0, 0);

  #pragma unroll 1
  for (int kt = 0; kt < NTK; ++kt) {
    int buf = kt & 1;
    stage(buf ^ 1, kt + 1);
    if (kt == NTK - 1) { VMC0(); } else { VMC6(); }
    BAR();
    const char* base = lds + buf * 24576;
    #pragma unroll
    for (int mi = 0; mi < 8; ++mi)
      a[mi] = *(const short8*)(base + aBase + mi * 1024);
    #pragma unroll
    for (int ni = 0; ni < 4; ++ni)
      b[ni] = *(const short8*)(base + bBase + ni * 1024);
    __builtin_amdgcn_s_setprio(1);
    #pragma unroll
    for (int mi = 0; mi < 8; ++mi)
      #pragma unroll
      for (int ni = 0; ni < 4; ++ni)
        acc[mi][ni] = __builtin_amdgcn_mfma_f32_16x16x32_bf16(
            a[mi], b[ni], acc[mi][ni], 0, 0, 0);
    __builtin_amdgcn_s_setprio(0);
    BAR();
  }

  // ---- fused epilogue: bias + GroupNorm(32) + SiLU * mw * SiLU ----
  // C/D frag: col = cb + ni*16 + llo ; row = rb + mi*16 + lhi*4 + j
  int cb = col0 + wn * 64;   // 2 groups of 32 per wave
  int rb = row0;

  float bias_v[4], mw_v[4];
  #pragma unroll
  for (int ni = 0; ni < 4; ++ni) {
    int c = cb + ni * 16 + llo;
    bias_v[ni] = bias[c];
    mw_v[ni] = mw[c];
  }
  #pragma unroll
  for (int mi = 0; mi < 8; ++mi)
    #pragma unroll
    for (int ni = 0; ni < 4; ++ni)
      #pragma unroll
      for (int j = 0; j < 4; ++j)
        acc[mi][ni][j] += bias_v[ni];

  #pragma unroll
  for (int mi = 0; mi < 8; ++mi) {
    #pragma unroll
    for (int gp = 0; gp < 2; ++gp) {
      int g = (cb >> 5) + gp;
      float gw = gnw[g], gb = gnb[g];
      float s[4], ss[4];
      #pragma unroll
      for (int j = 0; j < 4; ++j) {
        float a0 = acc[mi][2 * gp][j];
        float a1 = acc[mi][2 * gp + 1][j];
        s[j] = a0 + a1;
        ss[j] = a0 * a0 + a1 * a1;
      }
      #pragma unroll
      for (int off = 1; off < 16; off <<= 1) {
        #pragma unroll
        for (int j = 0; j < 4; ++j) {
          s[j]  += __shfl_xor(s[j],  off, 64);
          ss[j] += __shfl_xor(ss[j], off, 64);
        }
      }
      #pragma unroll
      for (int j = 0; j < 4; ++j) {
        float mean = s[j] * (1.0f / 32.0f);
        float var  = ss[j] * (1.0f / 32.0f) - mean * mean;
        float rstd = rsqrtf(var + EPSV);
        int r = rb + mi * 16 + lhi * 4 + j;
        #pragma unroll
        for (int nn = 0; nn < 2; ++nn) {
          int ni = 2 * gp + nn;
          float v = (acc[mi][ni][j] - mean) * rstd * gw + gb;
          v = v / (1.0f + __expf(-v));   // SiLU
          v = v * mw_v[ni];
          v = v / (1.0f + __expf(-v));   // SiLU
          out[(size_t)r * NN + (cb + ni * 16 + llo)] = v;
        }
      }
    }
  }
}

// ---------------- naive f32 fallback (only if ws too small) ----------------
__global__ void naive_gemm(const float* __restrict__ x, const float* __restrict__ w,
                           const float* __restrict__ bias, float* __restrict__ out) {
  size_t idx = (size_t)blockIdx.x * 256 + threadIdx.x;
  int m = (int)(idx >> 11);
  int n = (int)(idx & 2047);
  const float* xr = x + (size_t)m * KK;
  const float* wr = w + (size_t)n * KK;
  float s = bias[n];
  for (int k = 0; k < KK; k += 4)
    s += xr[k] * wr[k] + xr[k+1] * wr[k+1] + xr[k+2] * wr[k+2] + xr[k+3] * wr[k+3];
  out[idx] = s;
}

__global__ void naive_post(float* __restrict__ out, const float* __restrict__ gnw,
                           const float* __restrict__ gnb, const float* __restrict__ mw) {
  size_t idx = (size_t)blockIdx.x * 256 + threadIdx.x;  // M*G
  int m = (int)(idx >> 6);
  int g = (int)(idx & 63);
  float* p = out + (size_t)m * NN + g * 32;
  float s = 0.f, ss = 0.f;
  for (int j = 0; j < 32; ++j) { float v = p[j]; s += v; ss += v * v; }
  float mean = s * (1.0f / 32.0f);
  float var  = ss * (1.0f / 32.0f) - mean * mean;
  float rstd = rsqrtf(var + EPSV);
  float gw = gnw[g], gb = gnb[g];
  for (int j = 0; j < 32; ++j) {
    float v = (p[j] - mean) * rstd * gw + gb;
    v = v / (1.0f + __expf(-v));
    v = v * mw[g * 32 + j];
    v = v / (1.0f + __expf(-v));
    p[j] = v;
  }
}

extern "C" void kernel_launch(void* const* d_in, const int* in_sizes, int n_in,
                              void* d_out, int out_size, void* d_ws, size_t ws_size,
                              hipStream_t stream) {
  const float* x    = (const float*)d_in[0];
  const float* wgt  = (const float*)d_in[1];
  const float* bias = (const float*)d_in[2];
  const float* gnw  = (const float*)d_in[3];
  const float* gnb  = (const float*)d_in[4];
  const float* mwp  = (const float*)d_in[5];
  float* out = (float*)d_out;

  size_t need = ((size_t)MM * KK + (size_t)NN * KK) * 2;
  if (ws_size >= need) {
    uint16_t* xbf = (uint16_t*)d_ws;
    uint16_t* wbf = xbf + (size_t)MM * KK;
    cvt_f32_to_bf16<<<2048, 256, 0, stream>>>(x, xbf, (MM * KK) / 4);
    cvt_f32_to_bf16<<<512, 256, 0, stream>>>(wgt, wbf, (NN * KK) / 4);
    (void)hipFuncSetAttribute((const void*)gemm_gn_silu_2b,
                              hipFuncAttributeMaxDynamicSharedMemorySize, 49152);
    gemm_gn_silu_2b<<<1024, 256, 49152, stream>>>(xbf, wbf, bias, gnw, gnb, mwp, out);
  } else {
    naive_gemm<<<(MM * (size_t)NN) / 256, 256, 0, stream>>>(x, wgt, bias, out);
    naive_post<<<(MM * GG) / 256, 256, 0, stream>>>(out, gnw, gnb, mwp);
  }
}

// Round 5
// 213.269 us; speedup vs baseline: 1.0713x; 1.0713x over previous
//
#include <hip/hip_runtime.h>
#include <stdint.h>

#define MM 16384
#define KK 2048
#define NN 2048
#define GG 64
#define EPSV 1e-5f
#define NT 32           // K tiles of 64
#define NITER 16        // NT/2

typedef short short8 __attribute__((ext_vector_type(8)));
typedef float floatx4 __attribute__((ext_vector_type(4)));

__device__ __forceinline__ uint16_t f2bf(float f) {
  uint32_t u = __float_as_uint(f);
  u = (u + 0x7fffu + ((u >> 16) & 1u)) >> 16;
  return (uint16_t)u;
}

__global__ void cvt_f32_to_bf16(const float* __restrict__ src,
                                uint16_t* __restrict__ dst, int n4) {
  int stride = gridDim.x * blockDim.x;
  for (int i = blockIdx.x * blockDim.x + threadIdx.x; i < n4; i += stride) {
    float4 v = reinterpret_cast<const float4*>(src)[i];
    ushort4 o;
    o.x = f2bf(v.x); o.y = f2bf(v.y); o.z = f2bf(v.z); o.w = f2bf(v.w);
    reinterpret_cast<ushort4*>(dst)[i] = o;
  }
}

__device__ __forceinline__ void gload_lds16(const void* g, void* l) {
  __builtin_amdgcn_global_load_lds(
      (const __attribute__((address_space(1))) void*)g,
      (__attribute__((address_space(3))) void*)l, 16, 0, 0);
}

// r5: NO memory clobbers on barrier/waitcnt — a "memory"-clobbered asm makes
// SIInsertWaitcnts emit s_waitcnt vmcnt(0) lgkmcnt(0) before it, which turned
// r2-r4 into drain-0 schedules (m218's degenerate case). Builtin barrier has
// no implicit waitcnt; counted vmcnt stays counted.
#define BAR()  __builtin_amdgcn_s_barrier()
#define VMC4() __asm__ volatile("s_waitcnt vmcnt(4)")
#define VMC0() __asm__ volatile("s_waitcnt vmcnt(0)")
#define SCHEDB() __builtin_amdgcn_sched_barrier(0)

// 256x256 tile, BK=64, 8 waves (2Mx4N), 8-phase schedule with counted vmcnt.
// LDS 128KB: buf b at b*65536: A[256r][64k] bf16 (+0), B[256c][64k] (+32768).
// T2 XOR swizzle ((row&7)<<4 on byte col) applied on read; global source
// pre-swizzled, LDS dest linear (rule #21). Fused bias+GN(32)+SiLU*mw*SiLU.
__global__ __launch_bounds__(512, 2)
void gemm_gn_silu_8p(const uint16_t* __restrict__ xb,  // M x K bf16
                     const uint16_t* __restrict__ wb,  // N x K bf16
                     const float* __restrict__ bias,   // N
                     const float* __restrict__ gnw,    // G
                     const float* __restrict__ gnb,    // G
                     const float* __restrict__ mw,     // N
                     float* __restrict__ out) {        // M x N f32
  extern __shared__ char lds[];   // 131072 bytes

  int bid = blockIdx.x;
  // XCD chunk swizzle: 512 blocks, 8 XCDs, 64 consecutive tiles per XCD.
  int wgs = ((bid & 7) << 6) | (bid >> 3);
  int tm = wgs >> 3;          // 0..63  (M tiles)
  int tn = wgs & 7;           // 0..7   (N tiles)
  int row0 = tm * 256;
  int col0 = tn * 256;

  int t = threadIdx.x;
  int lane = t & 63;
  int wid = t >> 6;
  int wm = wid >> 2, wn = wid & 3;   // 2x4 wave grid
  int llo = lane & 15, lhi = lane >> 4;
  int sw = (llo & 7) << 4;

  const char* xgb = (const char*)xb + (size_t)row0 * (KK * 2);
  const char* wgb = (const char*)wb + (size_t)col0 * (KK * 2);

  // staging addresses: thread t covers half-tile bytes [t*16, t*16+16) and
  // [t*16+8192, ...). LDS dest linear; source column pre-swizzled.
  int o16 = t * 16;                 // 0..8176
  int srow = o16 >> 7;              // 0..63
  int spb = (o16 & 127) ^ ((srow & 7) << 4);
  const char* gaSrc = xgb + (size_t)srow * (KK * 2) + spb;
  const char* gbSrc = wgb + (size_t)srow * (KK * 2) + spb;

  auto stageA = [&](int buf, int h, int kt) {
    if (kt < NT) {
      const char* s = gaSrc + (size_t)h * (128 * KK * 2) + (size_t)kt * 128;
      char* d = lds + buf * 65536 + h * 16384 + o16;
      gload_lds16(s, d);
      gload_lds16(s + 64 * (KK * 2), d + 8192);
    }
  };
  auto stageB = [&](int buf, int h, int kt) {
    if (kt < NT) {
      const char* s = gbSrc + (size_t)h * (128 * KK * 2) + (size_t)kt * 128;
      char* d = lds + buf * 65536 + 32768 + h * 16384 + o16;
      gload_lds16(s, d);
      gload_lds16(s + 64 * (KK * 2), d + 8192);
    }
  };

  // Precomputed LDS byte offsets for fragment reads: [buf][kk].
  // row = (wm*128 + llo) + mh*64 + mi2*16; (row&7)==llo&7 for all frags, so
  // the swizzled k-offset ((kk*64 + lhi*16)^sw) is fragment-invariant and the
  // fragment selector (mh*8192 + mi2*2048) is a compile-time immediate.
  uint32_t aOff[2][2], bOff[2][2];
  #pragma unroll
  for (int buf = 0; buf < 2; ++buf)
    #pragma unroll
    for (int kk = 0; kk < 2; ++kk) {
      uint32_t ko = (uint32_t)((kk * 64 + lhi * 16) ^ sw);
      aOff[buf][kk] = buf * 65536u + (uint32_t)(wm * 128 + llo) * 128u + ko;
      bOff[buf][kk] = buf * 65536u + 32768u + (uint32_t)(wn * 64 + llo) * 128u + ko;
    }

  short8 a[4][2], blo[2][2], bhi[2][2];

  floatx4 acc[8][4] = {};

#define RDA(buf, mh)                                                       \
  {                                                                        \
    _Pragma("unroll") for (int kk = 0; kk < 2; ++kk)                       \
        _Pragma("unroll") for (int mi2 = 0; mi2 < 4; ++mi2)                \
            a[mi2][kk] = *(const short8*)(lds + aOff[buf][kk] +            \
                                          (mh)*8192 + mi2 * 2048);         \
  }
#define RDB(buf, nh, bq)                                                   \
  {                                                                        \
    _Pragma("unroll") for (int kk = 0; kk < 2; ++kk)                       \
        _Pragma("unroll") for (int ni2 = 0; ni2 < 2; ++ni2)                \
            bq[ni2][kk] = *(const short8*)(lds + bOff[buf][kk] +           \
                                           (nh)*4096 + ni2 * 2048);        \
  }
  // kk OUTER: 8 independent MFMAs between accumulator reuse (dep distance 8).
#define MFMAQ(mh, nh, bq)                                                  \
  {                                                                        \
    __builtin_amdgcn_s_setprio(1);                                         \
    _Pragma("unroll") for (int kk = 0; kk < 2; ++kk)                       \
        _Pragma("unroll") for (int mi2 = 0; mi2 < 4; ++mi2)                \
            _Pragma("unroll") for (int ni2 = 0; ni2 < 2; ++ni2)            \
                acc[(mh)*4 + mi2][(nh)*2 + ni2] =                          \
                    __builtin_amdgcn_mfma_f32_16x16x32_bf16(               \
                        a[mi2][kk], bq[ni2][kk],                           \
                        acc[(mh)*4 + mi2][(nh)*2 + ni2], 0, 0, 0);         \
    __builtin_amdgcn_s_setprio(0);                                         \
  }

  // Prologue: tile0 (B,A all halves) + tile1 B halves = 12 loads.
  stageB(0, 0, 0); stageB(0, 1, 0);
  stageA(0, 0, 0); stageA(0, 1, 0);
  stageB(1, 0, 1); stageB(1, 1, 1);
  VMC4();   // tile0's 8 loads landed; tile1 B (4) may stay in flight
  SCHEDB();
  BAR();

  #pragma unroll 1
  for (int i = 0; i < NITER; ++i) {
    int t1 = 2 * i + 1, t2 = 2 * i + 2, t3 = 2 * i + 3;
    // ---- K-tile 2i in buf0 ----
    // p1: quadrant (mh0, nh0)
    RDA(0, 0); RDB(0, 0, blo);
    stageA(1, 0, t1);
    BAR(); MFMAQ(0, 0, blo); BAR();
    // p2: (mh0, nh1)
    RDB(0, 1, bhi);
    stageA(1, 1, t1);
    BAR(); MFMAQ(0, 1, bhi); BAR();
    // p3: (mh1, nh1)
    RDA(0, 1);
    stageB(0, 0, t2);
    BAR(); MFMAQ(1, 1, bhi); BAR();
    // p4: (mh1, nh0)
    stageB(0, 1, t2);
    BAR(); MFMAQ(1, 0, blo);
    if (i == NITER - 1) { VMC0(); } else { VMC4(); }
    SCHEDB();
    BAR();
    SCHEDB();
    // ---- K-tile 2i+1 in buf1 ----
    // p5
    RDA(1, 0); RDB(1, 0, blo);
    stageA(0, 0, t2);
    BAR(); MFMAQ(0, 0, blo); BAR();
    // p6
    RDB(1, 1, bhi);
    stageA(0, 1, t2);
    BAR(); MFMAQ(0, 1, bhi); BAR();
    // p7
    RDA(1, 1);
    stageB(1, 0, t3);
    BAR(); MFMAQ(1, 1, bhi); BAR();
    // p8
    stageB(1, 1, t3);
    BAR(); MFMAQ(1, 0, blo);
    if (i < NITER - 1) { VMC4(); }
    SCHEDB();
    BAR();
    SCHEDB();
  }

  // ---- fused epilogue: bias + GroupNorm(32) + SiLU * mw * SiLU ----
  // C/D frag: col = cb + ni*16 + llo ; row = rb + mi*16 + lhi*4 + j
  int cb = col0 + wn * 64;   // 2 groups of 32 per wave
  int rb = row0 + wm * 128;

  float bias_v[4], mw_v[4];
  #pragma unroll
  for (int ni = 0; ni < 4; ++ni) {
    int c = cb + ni * 16 + llo;
    bias_v[ni] = bias[c];
    mw_v[ni] = mw[c];
  }
  #pragma unroll
  for (int mi = 0; mi < 8; ++mi)
    #pragma unroll
    for (int ni = 0; ni < 4; ++ni)
      #pragma unroll
      for (int j = 0; j < 4; ++j)
        acc[mi][ni][j] += bias_v[ni];

  #pragma unroll
  for (int mi = 0; mi < 8; ++mi) {
    #pragma unroll
    for (int gp = 0; gp < 2; ++gp) {
      int g = (cb >> 5) + gp;
      float gw = gnw[g], gb = gnb[g];
      float s[4], ss[4];
      #pragma unroll
      for (int j = 0; j < 4; ++j) {
        float a0 = acc[mi][2 * gp][j];
        float a1 = acc[mi][2 * gp + 1][j];
        s[j] = a0 + a1;
        ss[j] = a0 * a0 + a1 * a1;
      }
      #pragma unroll
      for (int off = 1; off < 16; off <<= 1) {
        #pragma unroll
        for (int j = 0; j < 4; ++j) {
          s[j]  += __shfl_xor(s[j],  off, 64);
          ss[j] += __shfl_xor(ss[j], off, 64);
        }
      }
      #pragma unroll
      for (int j = 0; j < 4; ++j) {
        float mean = s[j] * (1.0f / 32.0f);
        float var  = ss[j] * (1.0f / 32.0f) - mean * mean;
        float rstd = rsqrtf(var + EPSV);
        int r = rb + mi * 16 + lhi * 4 + j;
        #pragma unroll
        for (int nn = 0; nn < 2; ++nn) {
          int ni = 2 * gp + nn;
          float v = (acc[mi][ni][j] - mean) * rstd * gw + gb;
          v = v / (1.0f + __expf(-v));   // SiLU
          v = v * mw_v[ni];
          v = v / (1.0f + __expf(-v));   // SiLU
          out[(size_t)r * NN + (cb + ni * 16 + llo)] = v;
        }
      }
    }
  }
}

// ---------------- naive f32 fallback (only if ws too small) ----------------
__global__ void naive_gemm(const float* __restrict__ x, const float* __restrict__ w,
                           const float* __restrict__ bias, float* __restrict__ out) {
  size_t idx = (size_t)blockIdx.x * 256 + threadIdx.x;
  int m = (int)(idx >> 11);
  int n = (int)(idx & 2047);
  const float* xr = x + (size_t)m * KK;
  const float* wr = w + (size_t)n * KK;
  float s = bias[n];
  for (int k = 0; k < KK; k += 4)
    s += xr[k] * wr[k] + xr[k+1] * wr[k+1] + xr[k+2] * wr[k+2] + xr[k+3] * wr[k+3];
  out[idx] = s;
}

__global__ void naive_post(float* __restrict__ out, const float* __restrict__ gnw,
                           const float* __restrict__ gnb, const float* __restrict__ mw) {
  size_t idx = (size_t)blockIdx.x * 256 + threadIdx.x;  // M*G
  int m = (int)(idx >> 6);
  int g = (int)(idx & 63);
  float* p = out + (size_t)m * NN + g * 32;
  float s = 0.f, ss = 0.f;
  for (int j = 0; j < 32; ++j) { float v = p[j]; s += v; ss += v * v; }
  float mean = s * (1.0f / 32.0f);
  float var  = ss * (1.0f / 32.0f) - mean * mean;
  float rstd = rsqrtf(var + EPSV);
  float gw = gnw[g], gb = gnb[g];
  for (int j = 0; j < 32; ++j) {
    float v = (p[j] - mean) * rstd * gw + gb;
    v = v / (1.0f + __expf(-v));
    v = v * mw[g * 32 + j];
    v = v / (1.0f + __expf(-v));
    p[j] = v;
  }
}

extern "C" void kernel_launch(void* const* d_in, const int* in_sizes, int n_in,
                              void* d_out, int out_size, void* d_ws, size_t ws_size,
                              hipStream_t stream) {
  const float* x    = (const float*)d_in[0];
  const float* wgt  = (const float*)d_in[1];
  const float* bias = (const float*)d_in[2];
  const float* gnw  = (const float*)d_in[3];
  const float* gnb  = (const float*)d_in[4];
  const float* mwp  = (const float*)d_in[5];
  float* out = (float*)d_out;

  size_t need = ((size_t)MM * KK + (size_t)NN * KK) * 2;
  if (ws_size >= need) {
    uint16_t* xbf = (uint16_t*)d_ws;
    uint16_t* wbf = xbf + (size_t)MM * KK;
    cvt_f32_to_bf16<<<2048, 256, 0, stream>>>(x, xbf, (MM * KK) / 4);
    cvt_f32_to_bf16<<<512, 256, 0, stream>>>(wgt, wbf, (NN * KK) / 4);
    (void)hipFuncSetAttribute((const void*)gemm_gn_silu_8p,
                              hipFuncAttributeMaxDynamicSharedMemorySize, 131072);
    gemm_gn_silu_8p<<<512, 512, 131072, stream>>>(xbf, wbf, bias, gnw, gnb, mwp, out);
  } else {
    naive_gemm<<<(MM * (size_t)NN) / 256, 256, 0, stream>>>(x, wgt, bias, out);
    naive_post<<<(MM * GG) / 256, 256, 0, stream>>>(out, gnw, gnb, mwp);
  }
}

// Round 6
// 209.742 us; speedup vs baseline: 1.0893x; 1.0168x over previous
//
#include <hip/hip_runtime.h>
#include <stdint.h>

#define MM 16384
#define KK 2048
#define NN 2048
#define GG 64
#define EPSV 1e-5f
#define NT 32           // K tiles of 64
#define NITER 16        // NT/2

typedef short short8 __attribute__((ext_vector_type(8)));
typedef float floatx4 __attribute__((ext_vector_type(4)));

__device__ __forceinline__ uint16_t f2bf(float f) {
  uint32_t u = __float_as_uint(f);
  u = (u + 0x7fffu + ((u >> 16) & 1u)) >> 16;
  return (uint16_t)u;
}

__global__ void cvt_f32_to_bf16(const float* __restrict__ src,
                                uint16_t* __restrict__ dst, int n4) {
  int stride = gridDim.x * blockDim.x;
  for (int i = blockIdx.x * blockDim.x + threadIdx.x; i < n4; i += stride) {
    float4 v = reinterpret_cast<const float4*>(src)[i];
    ushort4 o;
    o.x = f2bf(v.x); o.y = f2bf(v.y); o.z = f2bf(v.z); o.w = f2bf(v.w);
    reinterpret_cast<ushort4*>(dst)[i] = o;
  }
}

__device__ __forceinline__ void gload_lds16(const void* g, void* l) {
  __builtin_amdgcn_global_load_lds(
      (const __attribute__((address_space(1))) void*)g,
      (__attribute__((address_space(3))) void*)l, 16, 0, 0);
}

#define SCHEDB() __builtin_amdgcn_sched_barrier(0)
// r6: RAW-ASM s_barrier. SIInsertWaitcnts special-cases the S_BARRIER machine
// instruction (builtin/__syncthreads) and inserts a full vmcnt(0) lgkmcnt(0)
// drain before it on targets without auto-waitcnt-before-barrier — which
// turned r2-r5 into drain-0 schedules. An inline-asm s_barrier is an opaque
// asm blob, not an S_BARRIER MI, so no drain is attached; the HW barrier
// still executes. sched_barrier(0) on both sides pins code motion (all
// cross-barrier orderings here are positional).
#define BAR()  { SCHEDB(); __asm__ volatile("s_barrier"); SCHEDB(); }
#define VMC4() __asm__ volatile("s_waitcnt vmcnt(4)")
#define VMC0() __asm__ volatile("s_waitcnt vmcnt(0)")

// DPP 16-lane row reduction: lanes [lhi*16 .. lhi*16+15] are one DPP row;
// 4 rotate-add steps give the full row sum in every lane. Pure VALU.
#define ROR_ADD(v, n)                                                      \
  v += __int_as_float(__builtin_amdgcn_update_dpp(                         \
      0, __float_as_int(v), 0x120 + (n), 0xF, 0xF, true))
#define ROW_REDUCE(v) { ROR_ADD(v, 1); ROR_ADD(v, 2); ROR_ADD(v, 4); ROR_ADD(v, 8); }

// 256x256 tile, BK=64, 8 waves (2Mx4N), 8-phase schedule with counted vmcnt.
// LDS 128KB: buf b at b*65536: A[256r][64k] bf16 (+0), B[256c][64k] (+32768).
// T2 XOR swizzle ((row&7)<<4 on byte col) applied on read; global source
// pre-swizzled, LDS dest linear (rule #21). Fused bias+GN(32)+SiLU*mw*SiLU.
__global__ __launch_bounds__(512, 2)
void gemm_gn_silu_8p(const uint16_t* __restrict__ xb,  // M x K bf16
                     const uint16_t* __restrict__ wb,  // N x K bf16
                     const float* __restrict__ bias,   // N
                     const float* __restrict__ gnw,    // G
                     const float* __restrict__ gnb,    // G
                     const float* __restrict__ mw,     // N
                     float* __restrict__ out) {        // M x N f32
  extern __shared__ char lds[];   // 131072 bytes

  int bid = blockIdx.x;
  // XCD chunk swizzle: 512 blocks, 8 XCDs, 64 consecutive tiles per XCD.
  int wgs = ((bid & 7) << 6) | (bid >> 3);
  int tm = wgs >> 3;          // 0..63  (M tiles)
  int tn = wgs & 7;           // 0..7   (N tiles)
  int row0 = tm * 256;
  int col0 = tn * 256;

  int t = threadIdx.x;
  int lane = t & 63;
  int wid = t >> 6;
  int wm = wid >> 2, wn = wid & 3;   // 2x4 wave grid
  int llo = lane & 15, lhi = lane >> 4;
  int sw = (llo & 7) << 4;

  const char* xgb = (const char*)xb + (size_t)row0 * (KK * 2);
  const char* wgb = (const char*)wb + (size_t)col0 * (KK * 2);

  // staging addresses: thread t covers half-tile bytes [t*16, t*16+16) and
  // [t*16+8192, ...). LDS dest linear; source column pre-swizzled.
  int o16 = t * 16;                 // 0..8176
  int srow = o16 >> 7;              // 0..63
  int spb = (o16 & 127) ^ ((srow & 7) << 4);
  const char* gaSrc = xgb + (size_t)srow * (KK * 2) + spb;
  const char* gbSrc = wgb + (size_t)srow * (KK * 2) + spb;

  auto stageA = [&](int buf, int h, int kt) {
    if (kt < NT) {
      const char* s = gaSrc + (size_t)h * (128 * KK * 2) + (size_t)kt * 128;
      char* d = lds + buf * 65536 + h * 16384 + o16;
      gload_lds16(s, d);
      gload_lds16(s + 64 * (KK * 2), d + 8192);
    }
  };
  auto stageB = [&](int buf, int h, int kt) {
    if (kt < NT) {
      const char* s = gbSrc + (size_t)h * (128 * KK * 2) + (size_t)kt * 128;
      char* d = lds + buf * 65536 + 32768 + h * 16384 + o16;
      gload_lds16(s, d);
      gload_lds16(s + 64 * (KK * 2), d + 8192);
    }
  };

  // Precomputed LDS byte offsets for fragment reads: [buf][kk].
  // row = (wm*128 + llo) + mh*64 + mi2*16; (row&7)==llo&7 for all frags, so
  // the swizzled k-offset ((kk*64 + lhi*16)^sw) is fragment-invariant and the
  // fragment selector (mh*8192 + mi2*2048) is a compile-time immediate.
  uint32_t aOff[2][2], bOff[2][2];
  #pragma unroll
  for (int buf = 0; buf < 2; ++buf)
    #pragma unroll
    for (int kk = 0; kk < 2; ++kk) {
      uint32_t ko = (uint32_t)((kk * 64 + lhi * 16) ^ sw);
      aOff[buf][kk] = buf * 65536u + (uint32_t)(wm * 128 + llo) * 128u + ko;
      bOff[buf][kk] = buf * 65536u + 32768u + (uint32_t)(wn * 64 + llo) * 128u + ko;
    }

  short8 a[4][2], blo[2][2], bhi[2][2];

  floatx4 acc[8][4] = {};

#define RDA(buf, mh)                                                       \
  {                                                                        \
    _Pragma("unroll") for (int kk = 0; kk < 2; ++kk)                       \
        _Pragma("unroll") for (int mi2 = 0; mi2 < 4; ++mi2)                \
            a[mi2][kk] = *(const short8*)(lds + aOff[buf][kk] +            \
                                          (mh)*8192 + mi2 * 2048);         \
  }
#define RDB(buf, nh, bq)                                                   \
  {                                                                        \
    _Pragma("unroll") for (int kk = 0; kk < 2; ++kk)                       \
        _Pragma("unroll") for (int ni2 = 0; ni2 < 2; ++ni2)                \
            bq[ni2][kk] = *(const short8*)(lds + bOff[buf][kk] +           \
                                           (nh)*4096 + ni2 * 2048);        \
  }
  // kk OUTER: 8 independent MFMAs between accumulator reuse (dep distance 8).
#define MFMAQ(mh, nh, bq)                                                  \
  {                                                                        \
    __builtin_amdgcn_s_setprio(1);                                         \
    _Pragma("unroll") for (int kk = 0; kk < 2; ++kk)                       \
        _Pragma("unroll") for (int mi2 = 0; mi2 < 4; ++mi2)                \
            _Pragma("unroll") for (int ni2 = 0; ni2 < 2; ++ni2)            \
                acc[(mh)*4 + mi2][(nh)*2 + ni2] =                          \
                    __builtin_amdgcn_mfma_f32_16x16x32_bf16(               \
                        a[mi2][kk], bq[ni2][kk],                           \
                        acc[(mh)*4 + mi2][(nh)*2 + ni2], 0, 0, 0);         \
    __builtin_amdgcn_s_setprio(0);                                         \
  }

  // Prologue: tile0 (B,A all halves) + tile1 B halves = 12 loads.
  stageB(0, 0, 0); stageB(0, 1, 0);
  stageA(0, 0, 0); stageA(0, 1, 0);
  stageB(1, 0, 1); stageB(1, 1, 1);
  VMC4();   // tile0's 8 loads landed; tile1 B (4) may stay in flight
  BAR();

  #pragma unroll 1
  for (int i = 0; i < NITER; ++i) {
    int t1 = 2 * i + 1, t2 = 2 * i + 2, t3 = 2 * i + 3;
    // ---- K-tile 2i in buf0 ----
    // p1: quadrant (mh0, nh0)
    RDA(0, 0); RDB(0, 0, blo);
    stageA(1, 0, t1);
    BAR(); MFMAQ(0, 0, blo); BAR();
    // p2: (mh0, nh1)
    RDB(0, 1, bhi);
    stageA(1, 1, t1);
    BAR(); MFMAQ(0, 1, bhi); BAR();
    // p3: (mh1, nh1)
    RDA(0, 1);
    stageB(0, 0, t2);
    BAR(); MFMAQ(1, 1, bhi); BAR();
    // p4: (mh1, nh0)
    stageB(0, 1, t2);
    BAR(); MFMAQ(1, 0, blo);
    if (i == NITER - 1) { VMC0(); } else { VMC4(); }
    BAR();
    // ---- K-tile 2i+1 in buf1 ----
    // p5
    RDA(1, 0); RDB(1, 0, blo);
    stageA(0, 0, t2);
    BAR(); MFMAQ(0, 0, blo); BAR();
    // p6
    RDB(1, 1, bhi);
    stageA(0, 1, t2);
    BAR(); MFMAQ(0, 1, bhi); BAR();
    // p7
    RDA(1, 1);
    stageB(1, 0, t3);
    BAR(); MFMAQ(1, 1, bhi); BAR();
    // p8
    stageB(1, 1, t3);
    BAR(); MFMAQ(1, 0, blo);
    if (i < NITER - 1) { VMC4(); }
    BAR();
  }

  // ---- fused epilogue: bias + GroupNorm(32) + SiLU * mw * SiLU ----
  // C/D frag: col = cb + ni*16 + llo ; row = rb + mi*16 + lhi*4 + j
  // Reduce groups = DPP rows (lanes lhi*16..lhi*16+15): pure-VALU row_ror.
  int cb = col0 + wn * 64;   // 2 groups of 32 per wave
  int rb = row0 + wm * 128;

  float bias_v[4], mw_v[4];
  #pragma unroll
  for (int ni = 0; ni < 4; ++ni) {
    int c = cb + ni * 16 + llo;
    bias_v[ni] = bias[c];
    mw_v[ni] = mw[c];
  }
  #pragma unroll
  for (int mi = 0; mi < 8; ++mi)
    #pragma unroll
    for (int ni = 0; ni < 4; ++ni)
      #pragma unroll
      for (int j = 0; j < 4; ++j)
        acc[mi][ni][j] += bias_v[ni];

  #pragma unroll
  for (int mi = 0; mi < 8; ++mi) {
    #pragma unroll
    for (int gp = 0; gp < 2; ++gp) {
      int g = (cb >> 5) + gp;
      float gw = gnw[g], gb = gnb[g];
      float s[4], ss[4];
      #pragma unroll
      for (int j = 0; j < 4; ++j) {
        float a0 = acc[mi][2 * gp][j];
        float a1 = acc[mi][2 * gp + 1][j];
        s[j] = a0 + a1;
        ss[j] = a0 * a0 + a1 * a1;
      }
      #pragma unroll
      for (int j = 0; j < 4; ++j) {
        ROW_REDUCE(s[j]);
        ROW_REDUCE(ss[j]);
      }
      #pragma unroll
      for (int j = 0; j < 4; ++j) {
        float mean = s[j] * (1.0f / 32.0f);
        float var  = ss[j] * (1.0f / 32.0f) - mean * mean;
        float rstd = rsqrtf(var + EPSV);
        int r = rb + mi * 16 + lhi * 4 + j;
        #pragma unroll
        for (int nn = 0; nn < 2; ++nn) {
          int ni = 2 * gp + nn;
          float v = (acc[mi][ni][j] - mean) * rstd * gw + gb;
          v = v / (1.0f + __expf(-v));   // SiLU
          v = v * mw_v[ni];
          v = v / (1.0f + __expf(-v));   // SiLU
          out[(size_t)r * NN + (cb + ni * 16 + llo)] = v;
        }
      }
    }
  }
}

// ---------------- naive f32 fallback (only if ws too small) ----------------
__global__ void naive_gemm(const float* __restrict__ x, const float* __restrict__ w,
                           const float* __restrict__ bias, float* __restrict__ out) {
  size_t idx = (size_t)blockIdx.x * 256 + threadIdx.x;
  int m = (int)(idx >> 11);
  int n = (int)(idx & 2047);
  const float* xr = x + (size_t)m * KK;
  const float* wr = w + (size_t)n * KK;
  float s = bias[n];
  for (int k = 0; k < KK; k += 4)
    s += xr[k] * wr[k] + xr[k+1] * wr[k+1] + xr[k+2] * wr[k+2] + xr[k+3] * wr[k+3];
  out[idx] = s;
}

__global__ void naive_post(float* __restrict__ out, const float* __restrict__ gnw,
                           const float* __restrict__ gnb, const float* __restrict__ mw) {
  size_t idx = (size_t)blockIdx.x * 256 + threadIdx.x;  // M*G
  int m = (int)(idx >> 6);
  int g = (int)(idx & 63);
  float* p = out + (size_t)m * NN + g * 32;
  float s = 0.f, ss = 0.f;
  for (int j = 0; j < 32; ++j) { float v = p[j]; s += v; ss += v * v; }
  float mean = s * (1.0f / 32.0f);
  float var  = ss * (1.0f / 32.0f) - mean * mean;
  float rstd = rsqrtf(var + EPSV);
  float gw = gnw[g], gb = gnb[g];
  for (int j = 0; j < 32; ++j) {
    float v = (p[j] - mean) * rstd * gw + gb;
    v = v / (1.0f + __expf(-v));
    v = v * mw[g * 32 + j];
    v = v / (1.0f + __expf(-v));
    p[j] = v;
  }
}

extern "C" void kernel_launch(void* const* d_in, const int* in_sizes, int n_in,
                              void* d_out, int out_size, void* d_ws, size_t ws_size,
                              hipStream_t stream) {
  const float* x    = (const float*)d_in[0];
  const float* wgt  = (const float*)d_in[1];
  const float* bias = (const float*)d_in[2];
  const float* gnw  = (const float*)d_in[3];
  const float* gnb  = (const float*)d_in[4];
  const float* mwp  = (const float*)d_in[5];
  float* out = (float*)d_out;

  size_t need = ((size_t)MM * KK + (size_t)NN * KK) * 2;
  if (ws_size >= need) {
    uint16_t* xbf = (uint16_t*)d_ws;
    uint16_t* wbf = xbf + (size_t)MM * KK;
    cvt_f32_to_bf16<<<2048, 256, 0, stream>>>(x, xbf, (MM * KK) / 4);
    cvt_f32_to_bf16<<<512, 256, 0, stream>>>(wgt, wbf, (NN * KK) / 4);
    (void)hipFuncSetAttribute((const void*)gemm_gn_silu_8p,
                              hipFuncAttributeMaxDynamicSharedMemorySize, 131072);
    gemm_gn_silu_8p<<<512, 512, 131072, stream>>>(xbf, wbf, bias, gnw, gnb, mwp, out);
  } else {
    naive_gemm<<<(MM * (size_t)NN) / 256, 256, 0, stream>>>(x, wgt, bias, out);
    naive_post<<<(MM * GG) / 256, 256, 0, stream>>>(out, gnw, gnb, mwp);
  }
}

// Round 7
// 207.459 us; speedup vs baseline: 1.1013x; 1.0110x over previous
//
#include <hip/hip_runtime.h>
#include <stdint.h>

#define MM 16384
#define KK 2048
#define NN 2048
#define GG 64
#define EPSV 1e-5f
#define NT 32           // K tiles of 64

typedef short short8 __attribute__((ext_vector_type(8)));
typedef float floatx4 __attribute__((ext_vector_type(4)));

__device__ __forceinline__ uint16_t f2bf(float f) {
  uint32_t u = __float_as_uint(f);
  u = (u + 0x7fffu + ((u >> 16) & 1u)) >> 16;
  return (uint16_t)u;
}

__global__ void cvt_f32_to_bf16(const float* __restrict__ src,
                                uint16_t* __restrict__ dst, int n4) {
  int stride = gridDim.x * blockDim.x;
  for (int i = blockIdx.x * blockDim.x + threadIdx.x; i < n4; i += stride) {
    float4 v = reinterpret_cast<const float4*>(src)[i];
    ushort4 o;
    o.x = f2bf(v.x); o.y = f2bf(v.y); o.z = f2bf(v.z); o.w = f2bf(v.w);
    reinterpret_cast<ushort4*>(dst)[i] = o;
  }
}

__device__ __forceinline__ void gload_lds16(const void* g, void* l) {
  __builtin_amdgcn_global_load_lds(
      (const __attribute__((address_space(1))) void*)g,
      (__attribute__((address_space(3))) void*)l, 16, 0, 0);
}

// DPP 16-lane row reduction: lanes [lhi*16 .. lhi*16+15] are one DPP row;
// 4 rotate-add steps give the full row sum in every lane. Pure VALU.
#define ROR_ADD(v, n)                                                      \
  v += __int_as_float(__builtin_amdgcn_update_dpp(                         \
      0, __float_as_int(v), 0x120 + (n), 0xF, 0xF, true))
#define ROW_REDUCE(v) { ROR_ADD(v, 1); ROR_ADD(v, 2); ROR_ADD(v, 4); ROR_ADD(v, 8); }

// r7: pipe-overlap structure. Per K-tile: stage(t+1) 8 gloads; ALL 24
// ds_read_b128 front-loaded (order a, blo, bhi, ah = earliest-needed first);
// 64 MFMA in quadrant rotation; ONE __syncthreads. No intra-tile barriers:
// r2-r6's 16-barrier lockstep forced LDS pipe (2300cyc/K-tile) and matrix
// pipe (2480cyc) into alternating bursts -> MfmaUtil pinned 33%. Compiler
// emits counted lgkmcnt before each quadrant's first MFMA use, so reads
// 13..24 overlap q0/q1 MFMA; waves desync in the 2-barrier window for
// cross-wave overlap. 1-tile-ahead prefetch: ~3000cyc compute hides ~900cyc
// HBM latency, so the end-of-tile vmcnt drain is free.
__global__ __launch_bounds__(512, 2)
void gemm_gn_silu_ol(const uint16_t* __restrict__ xb,  // M x K bf16
                     const uint16_t* __restrict__ wb,  // N x K bf16
                     const float* __restrict__ bias,   // N
                     const float* __restrict__ gnw,    // G
                     const float* __restrict__ gnb,    // G
                     const float* __restrict__ mw,     // N
                     float* __restrict__ out) {        // M x N f32
  extern __shared__ char lds[];   // 131072 bytes

  int bid = blockIdx.x;
  // XCD chunk swizzle: 512 blocks, 8 XCDs, 64 consecutive tiles per XCD.
  int wgs = ((bid & 7) << 6) | (bid >> 3);
  int tm = wgs >> 3;          // 0..63  (M tiles)
  int tn = wgs & 7;           // 0..7   (N tiles)
  int row0 = tm * 256;
  int col0 = tn * 256;

  int t = threadIdx.x;
  int lane = t & 63;
  int wid = t >> 6;
  int wm = wid >> 2, wn = wid & 3;   // 2x4 wave grid
  int llo = lane & 15, lhi = lane >> 4;
  int sw = (llo & 7) << 4;

  const char* xgb = (const char*)xb + (size_t)row0 * (KK * 2);
  const char* wgb = (const char*)wb + (size_t)col0 * (KK * 2);

  // staging addresses: LDS dest linear; source column pre-swizzled (rule #21).
  int o16 = t * 16;                 // 0..8176
  int srow = o16 >> 7;              // 0..63
  int spb = (o16 & 127) ^ ((srow & 7) << 4);
  const char* gaSrc = xgb + (size_t)srow * (KK * 2) + spb;
  const char* gbSrc = wgb + (size_t)srow * (KK * 2) + spb;

  auto stageA = [&](int buf, int h, int kt) {
    if (kt < NT) {
      const char* s = gaSrc + (size_t)h * (128 * KK * 2) + (size_t)kt * 128;
      char* d = lds + buf * 65536 + h * 16384 + o16;
      gload_lds16(s, d);
      gload_lds16(s + 64 * (KK * 2), d + 8192);
    }
  };
  auto stageB = [&](int buf, int h, int kt) {
    if (kt < NT) {
      const char* s = gbSrc + (size_t)h * (128 * KK * 2) + (size_t)kt * 128;
      char* d = lds + buf * 65536 + 32768 + h * 16384 + o16;
      gload_lds16(s, d);
      gload_lds16(s + 64 * (KK * 2), d + 8192);
    }
  };

  // Precomputed LDS byte offsets: row = (wm*128+llo)+mh*64+mi2*16; (row&7)
  // == llo&7 for all frags -> swizzled k-offset fragment-invariant, fragment
  // selector is a compile-time immediate.
  uint32_t aOff[2][2], bOff[2][2];
  #pragma unroll
  for (int buf = 0; buf < 2; ++buf)
    #pragma unroll
    for (int kk = 0; kk < 2; ++kk) {
      uint32_t ko = (uint32_t)((kk * 64 + lhi * 16) ^ sw);
      aOff[buf][kk] = buf * 65536u + (uint32_t)(wm * 128 + llo) * 128u + ko;
      bOff[buf][kk] = buf * 65536u + 32768u + (uint32_t)(wn * 64 + llo) * 128u + ko;
    }

  short8 a[4][2], ah[4][2], blo[2][2], bhi[2][2];
  floatx4 acc[8][4] = {};

#define RDA(buf, mh, aa)                                                   \
  {                                                                        \
    _Pragma("unroll") for (int kk = 0; kk < 2; ++kk)                       \
        _Pragma("unroll") for (int mi2 = 0; mi2 < 4; ++mi2)                \
            aa[mi2][kk] = *(const short8*)(lds + aOff[buf][kk] +           \
                                           (mh)*8192 + mi2 * 2048);        \
  }
#define RDB(buf, nh, bq)                                                   \
  {                                                                        \
    _Pragma("unroll") for (int kk = 0; kk < 2; ++kk)                       \
        _Pragma("unroll") for (int ni2 = 0; ni2 < 2; ++ni2)                \
            bq[ni2][kk] = *(const short8*)(lds + bOff[buf][kk] +           \
                                           (nh)*4096 + ni2 * 2048);        \
  }
  // kk OUTER: 8 independent MFMAs between accumulator reuse.
#define MFMAQ(mh, nh, bq, aa)                                              \
  {                                                                        \
    _Pragma("unroll") for (int kk = 0; kk < 2; ++kk)                       \
        _Pragma("unroll") for (int mi2 = 0; mi2 < 4; ++mi2)                \
            _Pragma("unroll") for (int ni2 = 0; ni2 < 2; ++ni2)            \
                acc[(mh)*4 + mi2][(nh)*2 + ni2] =                          \
                    __builtin_amdgcn_mfma_f32_16x16x32_bf16(               \
                        aa[mi2][kk], bq[ni2][kk],                          \
                        acc[(mh)*4 + mi2][(nh)*2 + ni2], 0, 0, 0);         \
  }

  // Prologue: stage tile 0 into buf 0, drain, sync.
  stageA(0, 0, 0); stageA(0, 1, 0);
  stageB(0, 0, 0); stageB(0, 1, 0);
  __syncthreads();   // implicit vmcnt(0) drain: tile0 resident

  #pragma unroll 1
  for (int kt = 0; kt < NT; ++kt) {
    int buf = kt & 1;
    // stage next tile into the other buffer (8 gloads, 1 tile ahead)
    stageA(buf ^ 1, 0, kt + 1); stageA(buf ^ 1, 1, kt + 1);
    stageB(buf ^ 1, 0, kt + 1); stageB(buf ^ 1, 1, kt + 1);
    // front-load ALL fragment reads, earliest-needed first
    if (buf == 0) { RDA(0, 0, a); RDB(0, 0, blo); RDB(0, 1, bhi); RDA(0, 1, ah); }
    else          { RDA(1, 0, a); RDB(1, 0, blo); RDB(1, 1, bhi); RDA(1, 1, ah); }
    // compute: quadrant rotation
    __builtin_amdgcn_s_setprio(1);
    MFMAQ(0, 0, blo, a);
    MFMAQ(0, 1, bhi, a);
    MFMAQ(1, 1, bhi, ah);
    MFMAQ(1, 0, blo, ah);
    __builtin_amdgcn_s_setprio(0);
    __syncthreads();   // one barrier per K-tile; drains stage loads (old)
  }

  // ---- fused epilogue: bias + GroupNorm(32) + SiLU * mw * SiLU ----
  // C/D frag: col = cb + ni*16 + llo ; row = rb + mi*16 + lhi*4 + j
  // Reduce groups = DPP rows (lanes lhi*16..lhi*16+15): pure-VALU row_ror.
  int cb = col0 + wn * 64;   // 2 groups of 32 per wave
  int rb = row0 + wm * 128;

  float bias_v[4], mw_v[4];
  #pragma unroll
  for (int ni = 0; ni < 4; ++ni) {
    int c = cb + ni * 16 + llo;
    bias_v[ni] = bias[c];
    mw_v[ni] = mw[c];
  }
  #pragma unroll
  for (int mi = 0; mi < 8; ++mi)
    #pragma unroll
    for (int ni = 0; ni < 4; ++ni)
      #pragma unroll
      for (int j = 0; j < 4; ++j)
        acc[mi][ni][j] += bias_v[ni];

  #pragma unroll
  for (int mi = 0; mi < 8; ++mi) {
    #pragma unroll
    for (int gp = 0; gp < 2; ++gp) {
      int g = (cb >> 5) + gp;
      float gw = gnw[g], gb = gnb[g];
      float s[4], ss[4];
      #pragma unroll
      for (int j = 0; j < 4; ++j) {
        float a0 = acc[mi][2 * gp][j];
        float a1 = acc[mi][2 * gp + 1][j];
        s[j] = a0 + a1;
        ss[j] = a0 * a0 + a1 * a1;
      }
      #pragma unroll
      for (int j = 0; j < 4; ++j) {
        ROW_REDUCE(s[j]);
        ROW_REDUCE(ss[j]);
      }
      #pragma unroll
      for (int j = 0; j < 4; ++j) {
        float mean = s[j] * (1.0f / 32.0f);
        float var  = ss[j] * (1.0f / 32.0f) - mean * mean;
        float rstd = rsqrtf(var + EPSV);
        int r = rb + mi * 16 + lhi * 4 + j;
        #pragma unroll
        for (int nn = 0; nn < 2; ++nn) {
          int ni = 2 * gp + nn;
          float v = (acc[mi][ni][j] - mean) * rstd * gw + gb;
          v = v / (1.0f + __expf(-v));   // SiLU
          v = v * mw_v[ni];
          v = v / (1.0f + __expf(-v));   // SiLU
          out[(size_t)r * NN + (cb + ni * 16 + llo)] = v;
        }
      }
    }
  }
}

// ---------------- naive f32 fallback (only if ws too small) ----------------
__global__ void naive_gemm(const float* __restrict__ x, const float* __restrict__ w,
                           const float* __restrict__ bias, float* __restrict__ out) {
  size_t idx = (size_t)blockIdx.x * 256 + threadIdx.x;
  int m = (int)(idx >> 11);
  int n = (int)(idx & 2047);
  const float* xr = x + (size_t)m * KK;
  const float* wr = w + (size_t)n * KK;
  float s = bias[n];
  for (int k = 0; k < KK; k += 4)
    s += xr[k] * wr[k] + xr[k+1] * wr[k+1] + xr[k+2] * wr[k+2] + xr[k+3] * wr[k+3];
  out[idx] = s;
}

__global__ void naive_post(float* __restrict__ out, const float* __restrict__ gnw,
                           const float* __restrict__ gnb, const float* __restrict__ mw) {
  size_t idx = (size_t)blockIdx.x * 256 + threadIdx.x;  // M*G
  int m = (int)(idx >> 6);
  int g = (int)(idx & 63);
  float* p = out + (size_t)m * NN + g * 32;
  float s = 0.f, ss = 0.f;
  for (int j = 0; j < 32; ++j) { float v = p[j]; s += v; ss += v * v; }
  float mean = s * (1.0f / 32.0f);
  float var  = ss * (1.0f / 32.0f) - mean * mean;
  float rstd = rsqrtf(var + EPSV);
  float gw = gnw[g], gb = gnb[g];
  for (int j = 0; j < 32; ++j) {
    float v = (p[j] - mean) * rstd * gw + gb;
    v = v / (1.0f + __expf(-v));
    v = v * mw[g * 32 + j];
    v = v / (1.0f + __expf(-v));
    p[j] = v;
  }
}

extern "C" void kernel_launch(void* const* d_in, const int* in_sizes, int n_in,
                              void* d_out, int out_size, void* d_ws, size_t ws_size,
                              hipStream_t stream) {
  const float* x    = (const float*)d_in[0];
  const float* wgt  = (const float*)d_in[1];
  const float* bias = (const float*)d_in[2];
  const float* gnw  = (const float*)d_in[3];
  const float* gnb  = (const float*)d_in[4];
  const float* mwp  = (const float*)d_in[5];
  float* out = (float*)d_out;

  size_t need = ((size_t)MM * KK + (size_t)NN * KK) * 2;
  if (ws_size >= need) {
    uint16_t* xbf = (uint16_t*)d_ws;
    uint16_t* wbf = xbf + (size_t)MM * KK;
    cvt_f32_to_bf16<<<2048, 256, 0, stream>>>(x, xbf, (MM * KK) / 4);
    cvt_f32_to_bf16<<<512, 256, 0, stream>>>(wgt, wbf, (NN * KK) / 4);
    (void)hipFuncSetAttribute((const void*)gemm_gn_silu_ol,
                              hipFuncAttributeMaxDynamicSharedMemorySize, 131072);
    gemm_gn_silu_ol<<<512, 512, 131072, stream>>>(xbf, wbf, bias, gnw, gnb, mwp, out);
  } else {
    naive_gemm<<<(MM * (size_t)NN) / 256, 256, 0, stream>>>(x, wgt, bias, out);
    naive_post<<<(MM * GG) / 256, 256, 0, stream>>>(out, gnw, gnb, mwp);
  }
}